// Round 4
// baseline (239.410 us; speedup 1.0000x reference)
//
#include <hip/hip_runtime.h>
#include <math.h>

// MLA decode attention (fp32), flash-decoding split over sequence chunks.
// B=64, H=16, latent D=576, V=512, MAX_LEN=4096.
//
// R3 change vs R2: 2-head register blocking + row-half split.
//  - Lane = (hg, dd): covers heads {base+2hg, base+2hg+1}, dim-slice dd.
//    Wave w: rowhalf = w>>1 (rows 0-7 / 8-15 of each tile), headhalf = w&1
//    (heads 0-7 / 8-15). Each ds_read_b128 now feeds TWO head-dots ->
//    LDS-read instruction count halves (was the ~92 us structural floor).
//  - Two dot chains (a,b) x 2 partials = 4 independent 18-deep FMA chains
//    per row (was one 36-deep chain).
//  - Softmax scale folded into Q registers at load (log2-domain scores).
//  - Row-halves merged in-block via LDS at chunk end (conflict-free
//    lane-consecutive layout); ws layout and reduce kernel unchanged.
//  - R1 lesson kept: no min-waves launch_bounds clamp, no manual unroll
//    pragmas on big bodies; all register arrays statically indexed.

namespace {
constexpr int NH = 16;
constexpr int MAXLEN = 4096;
constexpr int D = 576;
constexpr int DV = 512;
constexpr int TR = 16;        // tile rows; LDS tile = TR*D*4 = 36864 B
constexpr float SCALE_LOG2E = 0.041666666666666664f * 1.4426950408889634f;
constexpr float NEGINF = -1e30f;
constexpr float THR2 = 8.0f;  // defer-max threshold (log2 domain)
}

__device__ __forceinline__ void gload_lds16(const void* g, void* l) {
    __builtin_amdgcn_global_load_lds(
        (const __attribute__((address_space(1))) void*)g,
        (__attribute__((address_space(3))) void*)l, 16, 0, 0);
}

__global__ __launch_bounds__(256)
void mla_chunk(const float* __restrict__ qg,
               const float* __restrict__ kvnew,
               const float* __restrict__ cache,
               const int* __restrict__ lens,
               float* __restrict__ ws_o,
               float* __restrict__ ws_ml,
               int nchunk, int chunk)
{
    const int c = blockIdx.x;
    const int b = blockIdx.y;
    const int tid = (int)threadIdx.x;

    const int total = lens[b] + 1;
    const int start = c * chunk;
    if (start >= total) return;          // uniform early-exit before barriers
    const int end = min(start + chunk, total);
    const int newpos = total - 1;

    __shared__ float kv_s[TR][D];        // 36864 B (reused for the merge)

    const int wave = tid >> 6;
    const int lane = tid & 63;
    const int hg = lane >> 4;            // head-pair group within wave
    const int dd = lane & 15;            // d-slice
    const int rowhalf = wave >> 1;       // 0: tile rows 0-7, 1: rows 8-15
    const int heada = (wave & 1) * 8 + hg * 2;   // covers heada, heada+1

    // Q for both heads into registers, softmax scale pre-folded (log2 dom.)
    float4 qa[9], qb[9];
    {
        const float* qp = qg + ((size_t)b * NH + heada) * D + dd * 4;
        #pragma unroll
        for (int j = 0; j < 9; ++j) {
            float4 va = *(const float4*)(qp + j * 64);
            float4 vb = *(const float4*)(qp + D + j * 64);
            va.x *= SCALE_LOG2E; va.y *= SCALE_LOG2E;
            va.z *= SCALE_LOG2E; va.w *= SCALE_LOG2E;
            vb.x *= SCALE_LOG2E; vb.y *= SCALE_LOG2E;
            vb.z *= SCALE_LOG2E; vb.w *= SCALE_LOG2E;
            qa[j] = va; qb[j] = vb;
        }
    }

    float4 acca[8], accb[8];
    #pragma unroll
    for (int j = 0; j < 8; ++j) {
        acca[j] = make_float4(0.f, 0.f, 0.f, 0.f);
        accb[j] = make_float4(0.f, 0.f, 0.f, 0.f);
    }
    float ma = NEGINF, la = 0.f;
    float mb = NEGINF, lb = 0.f;

    for (int r0 = start; r0 < end; r0 += TR) {
        const int nrows = min(TR, end - r0);
        // ---- stage 16 rows -> LDS (rows beyond `end` staged, never read)
        {
            const char* src = (const char*)(cache + ((size_t)b * MAXLEN + r0) * D);
            char* dst = (char*)&kv_s[0][0];
            const int o = tid * 16;
            #pragma unroll
            for (int it = 0; it < 9; ++it)
                gload_lds16(src + it * 4096 + o, dst + it * 4096 + o);
        }
        __syncthreads();
        if (newpos >= r0 && newpos < r0 + TR) {   // block-uniform condition
            if (tid < D / 4)
                ((float4*)&kv_s[newpos - r0][0])[tid] =
                    ((const float4*)(kvnew + (size_t)b * D))[tid];
            __syncthreads();
        }

        // ---- this wave's row-half: score + softmax + PV, no barriers ----
        const int rbeg = rowhalf * 8;
        const int rend = min(rbeg + 8, nrows);
        for (int r = rbeg; r < rend; ++r) {
            const float* krow = &kv_s[r][0];
            float4 x[9];
            #pragma unroll
            for (int j = 0; j < 9; ++j)
                x[j] = *(const float4*)(krow + j * 64 + dd * 4);

            float sa0 = 0.f, sa1 = 0.f, sb0 = 0.f, sb1 = 0.f;
            #pragma unroll
            for (int j = 0; j < 9; ++j) {
                if (j & 1) {
                    sa1 = fmaf(x[j].x, qa[j].x, sa1);
                    sa1 = fmaf(x[j].y, qa[j].y, sa1);
                    sa1 = fmaf(x[j].z, qa[j].z, sa1);
                    sa1 = fmaf(x[j].w, qa[j].w, sa1);
                    sb1 = fmaf(x[j].x, qb[j].x, sb1);
                    sb1 = fmaf(x[j].y, qb[j].y, sb1);
                    sb1 = fmaf(x[j].z, qb[j].z, sb1);
                    sb1 = fmaf(x[j].w, qb[j].w, sb1);
                } else {
                    sa0 = fmaf(x[j].x, qa[j].x, sa0);
                    sa0 = fmaf(x[j].y, qa[j].y, sa0);
                    sa0 = fmaf(x[j].z, qa[j].z, sa0);
                    sa0 = fmaf(x[j].w, qa[j].w, sa0);
                    sb0 = fmaf(x[j].x, qb[j].x, sb0);
                    sb0 = fmaf(x[j].y, qb[j].y, sb0);
                    sb0 = fmaf(x[j].z, qb[j].z, sb0);
                    sb0 = fmaf(x[j].w, qb[j].w, sb0);
                }
            }
            float sa = sa0 + sa1;
            float sb = sb0 + sb1;
            // butterfly over the 16-lane dd-group (both heads interleaved)
            #pragma unroll
            for (int m = 1; m <= 8; m <<= 1) {
                sa += __shfl_xor(sa, m);
                sb += __shfl_xor(sb, m);
            }

            float pa, pb;
            if (sa > ma + THR2) {        // rare rescale (defer-max)
                const float scl = exp2f(ma - sa);
                ma = sa; la *= scl;
                #pragma unroll
                for (int j = 0; j < 8; ++j) {
                    acca[j].x *= scl; acca[j].y *= scl;
                    acca[j].z *= scl; acca[j].w *= scl;
                }
                pa = 1.f;
            } else {
                pa = exp2f(sa - ma);
            }
            la += pa;
            if (sb > mb + THR2) {
                const float scl = exp2f(mb - sb);
                mb = sb; lb *= scl;
                #pragma unroll
                for (int j = 0; j < 8; ++j) {
                    accb[j].x *= scl; accb[j].y *= scl;
                    accb[j].z *= scl; accb[j].w *= scl;
                }
                pb = 1.f;
            } else {
                pb = exp2f(sb - mb);
            }
            lb += pb;

            #pragma unroll
            for (int j = 0; j < 8; ++j) {
                acca[j].x = fmaf(pa, x[j].x, acca[j].x);
                acca[j].y = fmaf(pa, x[j].y, acca[j].y);
                acca[j].z = fmaf(pa, x[j].z, acca[j].z);
                acca[j].w = fmaf(pa, x[j].w, acca[j].w);
                accb[j].x = fmaf(pb, x[j].x, accb[j].x);
                accb[j].y = fmaf(pb, x[j].y, accb[j].y);
                accb[j].z = fmaf(pb, x[j].z, accb[j].z);
                accb[j].w = fmaf(pb, x[j].w, accb[j].w);
            }
        }
        __syncthreads();                 // protect kv_s before next stage
    }

    // ---- in-block merge of row-halves via LDS (conflict-free layout) ----
    float* mrg = (float*)&kv_s[0][0];
    if (rowhalf == 1) {
        const int w2 = wave - 2;         // 0 or 1
        #pragma unroll
        for (int j = 0; j < 8; ++j) {
            *(float4*)&mrg[w2 * 4096 + j * 256 + lane * 4] = acca[j];
            *(float4*)&mrg[w2 * 4096 + (8 + j) * 256 + lane * 4] = accb[j];
        }
        float* mlp = &mrg[8192 + w2 * 256 + lane * 4];
        mlp[0] = ma; mlp[1] = la; mlp[2] = mb; mlp[3] = lb;
    }
    __syncthreads();
    if (rowhalf == 0) {
        const int w2 = wave;             // partner wave = wave+2
        const float* mlp = &mrg[8192 + w2 * 256 + lane * 4];
        const float ma2 = mlp[0], la2 = mlp[1];
        const float mb2 = mlp[2], lb2 = mlp[3];

        const float mna = fmaxf(ma, ma2);
        const float wa1 = exp2f(ma - mna), wa2 = exp2f(ma2 - mna);
        la = la * wa1 + la2 * wa2;
        const float mnb = fmaxf(mb, mb2);
        const float wb1 = exp2f(mb - mnb), wb2 = exp2f(mb2 - mnb);
        lb = lb * wb1 + lb2 * wb2;

        #pragma unroll
        for (int j = 0; j < 8; ++j) {
            const float4 a2 = *(const float4*)&mrg[w2 * 4096 + j * 256 + lane * 4];
            const float4 b2 = *(const float4*)&mrg[w2 * 4096 + (8 + j) * 256 + lane * 4];
            acca[j].x = acca[j].x * wa1 + a2.x * wa2;
            acca[j].y = acca[j].y * wa1 + a2.y * wa2;
            acca[j].z = acca[j].z * wa1 + a2.z * wa2;
            acca[j].w = acca[j].w * wa1 + a2.w * wa2;
            accb[j].x = accb[j].x * wb1 + b2.x * wb2;
            accb[j].y = accb[j].y * wb1 + b2.y * wb2;
            accb[j].z = accb[j].z * wb1 + b2.z * wb2;
            accb[j].w = accb[j].w * wb1 + b2.w * wb2;
        }

        // ---- write partials: dims {j*64+dd*4..+3} of heads a, a+1 ----
        float* opa = ws_o + (((size_t)b * nchunk + c) * NH + heada) * DV + dd * 4;
        #pragma unroll
        for (int j = 0; j < 8; ++j) {
            *(float4*)(opa + j * 64) = acca[j];
            *(float4*)(opa + (size_t)DV + j * 64) = accb[j];
        }
        if (dd == 0) {
            const size_t mlb = (((size_t)b * nchunk + c) * NH + heada) * 2;
            ws_ml[mlb]     = fmaxf(ma, ma2);
            ws_ml[mlb + 1] = la;
            ws_ml[mlb + 2] = fmaxf(mb, mb2);
            ws_ml[mlb + 3] = lb;
        }
    }
}

__global__ __launch_bounds__(256)
void mla_reduce(const int* __restrict__ lens,
                const float* __restrict__ ws_o,
                const float* __restrict__ ws_ml,
                float* __restrict__ out,
                int nchunk, int chunk)
{
    const int h = blockIdx.x;
    const int b = blockIdx.y;
    const int tid = (int)threadIdx.x;
    const int total = lens[b] + 1;
    const int nact = min(nchunk, (total + chunk - 1) / chunk);

    float M = NEGINF;
    for (int c = 0; c < nact; ++c)
        M = fmaxf(M, ws_ml[(((size_t)b * nchunk + c) * NH + h) * 2]);

    float a0 = 0.f, a1 = 0.f, L = 0.f;
    for (int c = 0; c < nact; ++c) {
        const size_t mlb = (((size_t)b * nchunk + c) * NH + h) * 2;
        const float w = exp2f(ws_ml[mlb] - M);   // log2-domain merge
        L += w * ws_ml[mlb + 1];
        const float2 o = *(const float2*)&ws_o[
            (((size_t)b * nchunk + c) * NH + h) * (size_t)DV + 2 * tid];
        a0 = fmaf(w, o.x, a0);
        a1 = fmaf(w, o.y, a1);
    }
    const float inv = 1.f / L;
    *(float2*)&out[((size_t)b * NH + h) * (size_t)DV + 2 * tid] =
        make_float2(a0 * inv, a1 * inv);
}

extern "C" void kernel_launch(void* const* d_in, const int* in_sizes, int n_in,
                              void* d_out, int out_size, void* d_ws, size_t ws_size,
                              hipStream_t stream)
{
    (void)in_sizes; (void)n_in; (void)out_size;
    const float* qg    = (const float*)d_in[0];   // [B,H,576]
    const float* kvnew = (const float*)d_in[1];   // [B,1,576]
    const float* cache = (const float*)d_in[2];   // [B,4096,576]
    const int*   lens  = (const int*)d_in[3];     // [B]
    float* out = (float*)d_out;                   // [B,H,512] fp32
    const int NB = 64;

    // largest chunk split that fits the workspace (67 MB at nchunk=32)
    int nchunk = 32;
    while (nchunk > 1 &&
           (size_t)NB * nchunk * NH * (DV + 2) * sizeof(float) > ws_size)
        nchunk >>= 1;
    const int chunk = MAXLEN / nchunk;

    float* ws_o  = (float*)d_ws;
    float* ws_ml = ws_o + (size_t)NB * nchunk * NH * DV;

    dim3 gA(nchunk, NB);
    mla_chunk<<<gA, 256, 0, stream>>>(qg, kvnew, cache, lens, ws_o, ws_ml,
                                      nchunk, chunk);
    dim3 gB(NH, NB);
    mla_reduce<<<gB, 256, 0, stream>>>(lens, ws_o, ws_ml, out, nchunk, chunk);
}